// Round 3
// baseline (442.993 us; speedup 1.0000x reference)
//
#include <hip/hip_runtime.h>
#include <hip/hip_bf16.h>
#include <stdint.h>

typedef short bf16x8 __attribute__((ext_vector_type(8)));
typedef short bf16x4 __attribute__((ext_vector_type(4)));
typedef float f32x4 __attribute__((ext_vector_type(4)));
typedef unsigned int u32x2 __attribute__((ext_vector_type(2)));
typedef unsigned int u32x4 __attribute__((ext_vector_type(4)));

__device__ __forceinline__ unsigned short f2bf(float f) {
  union { float f; unsigned u; } x; x.f = f;
  unsigned r = x.u + 0x7FFFu + ((x.u >> 16) & 1u);
  return (unsigned short)(r >> 16);
}

// packed 2xf32 -> 2xbf16 (v_cvt_pk_bf16_f32 on gfx950)
__device__ __forceinline__ unsigned pk2bf(float a, float b) {
  union { __hip_bfloat162 h; unsigned u; } x;
  x.h = __float22bfloat162_rn(make_float2(a, b));
  return x.u;
}

typedef const __attribute__((address_space(1))) unsigned int* gptr_t;
typedef __attribute__((address_space(3))) unsigned int* lptr_t;
__device__ __forceinline__ void gll16(const void* g, void* l) {
  __builtin_amdgcn_global_load_lds((gptr_t)g, (lptr_t)l, 16, 0, 0);
}

// ---------------- W transpose: [K=1024][N=1024] fp32 -> [N][K] bf16 ----------
__global__ __launch_bounds__(1024) void wt_kernel(const float* __restrict__ Wq,
                                                  const float* __restrict__ Wk,
                                                  const float* __restrict__ Wv,
                                                  unsigned short* __restrict__ wt) {
  const float* W = blockIdx.z == 0 ? Wq : (blockIdx.z == 1 ? Wk : Wv);
  unsigned short* o = wt + (size_t)blockIdx.z * 1048576;
  __shared__ float t[32][33];
  int tx = threadIdx.x, ty = threadIdx.y;
  t[ty][tx] = W[(size_t)(blockIdx.y * 32 + ty) * 1024 + blockIdx.x * 32 + tx];
  __syncthreads();
  o[(size_t)(blockIdx.x * 32 + ty) * 1024 + blockIdx.y * 32 + tx] = f2bf(t[tx][ty]);
}

// ---------------- X fp32 -> bf16 (Q,K,V concatenated) ------------------------
__global__ __launch_bounds__(256) void cvt_kernel(const float* __restrict__ Q,
                                                  const float* __restrict__ K,
                                                  const float* __restrict__ V,
                                                  unsigned short* __restrict__ out) {
  int y = blockIdx.y;
  const float* s = y == 0 ? Q : (y == 1 ? K : V);
  unsigned short* o = out + (size_t)y * 8388608;
  size_t idx = ((size_t)blockIdx.x * 256 + threadIdx.x) * 8;
  float4 f0 = *(const float4*)(s + idx);
  float4 f1 = *(const float4*)(s + idx + 4);
  u32x4 r = {pk2bf(f0.x, f0.y), pk2bf(f0.z, f0.w), pk2bf(f1.x, f1.y), pk2bf(f1.z, f1.w)};
  *(u32x4*)(o + idx) = r;
}

// ---------------- projection GEMM: C[8192,1024] = Xb @ W^T + b ---------------
__global__ __launch_bounds__(256) void proj_kernel(
    const unsigned short* __restrict__ Xb, const unsigned short* __restrict__ wt,
    const float* __restrict__ bq, const float* __restrict__ bk, const float* __restrict__ bv,
    unsigned short* __restrict__ qo, unsigned short* __restrict__ ko, unsigned short* __restrict__ vo) {
  int p = blockIdx.z;
  const unsigned short* X = Xb + (size_t)p * 8388608;
  const unsigned short* Wt = wt + (size_t)p * 1048576;
  const float* bias = p == 0 ? bq : (p == 1 ? bk : bv);
  unsigned short* out = p == 0 ? qo : (p == 1 ? ko : vo);

  __shared__ __align__(16) unsigned short abuf[8192];  // 16KB
  __shared__ __align__(16) unsigned short bbuf[8192];  // 16KB

  int tid = threadIdx.x;
  int lane = tid & 63, w = tid >> 6;
  int l15 = lane & 15, quad = lane >> 4;
  int wm = w >> 1, wn = w & 1;
  int m0 = blockIdx.x * 128, n0 = blockIdx.y * 128;

  f32x4 acc[4][4] = {};

  for (int kk = 0; kk < 16; ++kk) {
    int k0 = kk * 64;
    for (int j = 0; j < 4; ++j) {
      int stj = w * 4 + j;
      int kt = stj >> 3, t = stj & 7;
      gll16(Wt + (size_t)(n0 + t * 16 + l15) * 1024 + k0 + kt * 32 + quad * 8, &bbuf[stj * 512]);
      gll16(X + (size_t)(m0 + t * 16 + l15) * 1024 + k0 + kt * 32 + quad * 8, &abuf[stj * 512]);
    }
    __syncthreads();
    for (int kt = 0; kt < 2; ++kt) {
      bf16x8 af[4], bfr[4];
      for (int i = 0; i < 4; ++i) af[i]  = *(const bf16x8*)&abuf[(kt * 8 + wm * 4 + i) * 512 + lane * 8];
      for (int j = 0; j < 4; ++j) bfr[j] = *(const bf16x8*)&bbuf[(kt * 8 + wn * 4 + j) * 512 + lane * 8];
      for (int i = 0; i < 4; ++i)
        for (int j = 0; j < 4; ++j)
          acc[i][j] = __builtin_amdgcn_mfma_f32_16x16x32_bf16(af[i], bfr[j], acc[i][j], 0, 0, 0);
    }
    __syncthreads();
  }

  // epilogue: +bias, cast bf16, scatter to q/k [B,H,S,64] or v^T [B,H,64,S]
  bool isv = (p == 2);
  for (int j = 0; j < 4; ++j) {
    int n = n0 + wn * 64 + j * 16 + l15;
    float bl = bias[n];
    int h = n >> 6, d = n & 63;
    for (int i = 0; i < 4; ++i) {
      for (int r = 0; r < 4; ++r) {
        int m = m0 + wm * 64 + i * 16 + quad * 4 + r;
        int b = m >> 11, s = m & 2047;
        float val = acc[i][j][r] + bl;
        size_t idx;
        if (isv) idx = ((size_t)((b * 16 + h) * 64 + d) << 11) + s;
        else     idx = ((size_t)((b * 16 + h) * 2048 + s) << 6) + d;
        out[idx] = f2bf(val);
      }
    }
  }
}

// ---------------- fused attention ------------------------------------------
// grid (16,16,4), 256 thr = 4 waves, wave owns 32 q-rows.
// S^T = K Q^T (16x16x32): lane holds P^T[key=quad*4+r][qrow=l15] — exactly the
// B-operand fragment of 16x16x16 MFMA. PV: O^T = V^T P^T with K=16 MFMAs,
// zero P data movement. den via ones-A MFMA. Epilogue transposes O^T in LDS.
__global__ __launch_bounds__(256, 4) void attn_kernel(
    const unsigned short* __restrict__ q, const unsigned short* __restrict__ k,
    const unsigned short* __restrict__ vT, const float* __restrict__ mask,
    float* __restrict__ out) {
  int qb = blockIdx.x, h = blockIdx.y, b = blockIdx.z;
  int tid = threadIdx.x, lane = tid & 63, w = tid >> 6;
  int l15 = lane & 15, quad = lane >> 4;

  __shared__ __align__(16) unsigned short smem[16384];  // 32KB: K(16) + V(16)
  unsigned short* kls = smem;
  unsigned short* vls = smem + 8192;

  const unsigned short* qp = q + (size_t)(b * 16 + h) * 2048 * 64;
  const unsigned short* kp = k + (size_t)(b * 16 + h) * 2048 * 64;
  const unsigned short* vp = vT + (size_t)(b * 16 + h) * 64 * 2048;
  const float* mp = mask + (size_t)b * 2048;

  // Q fragments (B-operand of S^T): qrow=l15, d=kt*32+quad*8+j
  bf16x8 aq[2][2];
  for (int nt = 0; nt < 2; ++nt)
    for (int kt = 0; kt < 2; ++kt)
      aq[nt][kt] = *(const bf16x8*)(qp + (size_t)(qb * 128 + w * 32 + nt * 16 + l15) * 64 + kt * 32 + quad * 8);

  f32x4 oacc[2][4] = {};  // O^T[dv-block][.]: row=dv-local, col=qrow-local
  f32x4 dacc[2] = {};     // den[qrow=l15] in every row
  bf16x4 ones4 = {0x3F80, 0x3F80, 0x3F80, 0x3F80};

  const float expc = 0.18033688011112042f;  // 0.125 * log2(e)
  int srclA = ((quad >> 1)) * 16 + l15;     // + (t&1)*32 added in loop
  int voff = (quad & 1) * 4;

  for (int kb = 0; kb < 16; ++kb) {
    int kbase = kb * 128;
    __syncthreads();  // previous iter's LDS reads complete before restaging
    for (int j = 0; j < 4; ++j) {
      int stj = w * 4 + j;
      int kt = stj >> 3, t = stj & 7;
      gll16(kp + (size_t)(kbase + t * 16 + l15) * 64 + kt * 32 + quad * 8, &kls[stj * 512]);
      int kt2 = stj >> 2, t2 = stj & 3;
      gll16(vp + (size_t)(t2 * 16 + l15) * 2048 + kbase + kt2 * 32 + quad * 8, &vls[stj * 512]);
    }
    __syncthreads();  // staging visible (compiler drains vmcnt before barrier)

    for (int t = 0; t < 8; ++t) {
      // S^T tile: D[key-local=quad*4+r][qrow=l15]
      f32x4 s0 = {}, s1 = {};
      for (int kt = 0; kt < 2; ++kt) {
        bf16x8 ak = *(const bf16x8*)&kls[(kt * 8 + t) * 512 + lane * 8];
        s0 = __builtin_amdgcn_mfma_f32_16x16x32_bf16(ak, aq[0][kt], s0, 0, 0, 0);
        s1 = __builtin_amdgcn_mfma_f32_16x16x32_bf16(ak, aq[1][kt], s1, 0, 0, 0);
      }
      // P^T = exp(S/8)*mask[key] packed bf16 — already in B-frag layout (k=quad*4+j)
      float4 mv = *(const float4*)&mp[kbase + t * 16 + quad * 4];
      float e00 = exp2f(s0[0] * expc) * mv.x, e01 = exp2f(s0[1] * expc) * mv.y;
      float e02 = exp2f(s0[2] * expc) * mv.z, e03 = exp2f(s0[3] * expc) * mv.w;
      float e10 = exp2f(s1[0] * expc) * mv.x, e11 = exp2f(s1[1] * expc) * mv.y;
      float e12 = exp2f(s1[2] * expc) * mv.z, e13 = exp2f(s1[3] * expc) * mv.w;
      union { u32x2 u; bf16x4 v; } p0, p1;
      p0.u = (u32x2){pk2bf(e00, e01), pk2bf(e02, e03)};
      p1.u = (u32x2){pk2bf(e10, e11), pk2bf(e12, e13)};

      dacc[0] = __builtin_amdgcn_mfma_f32_16x16x16bf16_1k(ones4, p0.v, dacc[0], 0, 0, 0);
      dacc[1] = __builtin_amdgcn_mfma_f32_16x16x16bf16_1k(ones4, p1.v, dacc[1], 0, 0, 0);

      int vbase = (t >> 1) * 2048 + ((t & 1) * 32 + srclA) * 8 + voff;
      for (int dvt = 0; dvt < 4; ++dvt) {
        bf16x4 av = *(const bf16x4*)&vls[vbase + dvt * 512];
        oacc[0][dvt] = __builtin_amdgcn_mfma_f32_16x16x16bf16_1k(av, p0.v, oacc[0][dvt], 0, 0, 0);
        oacc[1][dvt] = __builtin_amdgcn_mfma_f32_16x16x16bf16_1k(av, p1.v, oacc[1][dvt], 0, 0, 0);
      }
    }
  }

  // epilogue: O^T -> O via per-wave LDS transpose, coalesced fp32 stores
  float* eb = (float*)smem;
  float* ew = eb + w * 1040;  // 16 rows x 65 floats per wave per pass
  for (int mt = 0; mt < 2; ++mt) {
    __syncthreads();
    float rden = 1.0f / (dacc[mt][0] + 1e-8f);
    for (int dvt = 0; dvt < 4; ++dvt)
      for (int r = 0; r < 4; ++r)
        ew[l15 * 65 + dvt * 16 + quad * 4 + r] = oacc[mt][dvt][r] * rden;
    __syncthreads();
    int row = lane >> 2, seg = lane & 3;
    const float* src = &ew[row * 65 + seg * 16];
    float* op = out + (size_t)(b * 2048 + qb * 128 + w * 32 + mt * 16 + row) * 1024 + h * 64 + seg * 16;
    for (int i = 0; i < 4; ++i)
      *(float4*)(op + i * 4) = *(const float4*)(src + i * 4);
  }
}

extern "C" void kernel_launch(void* const* d_in, const int* in_sizes, int n_in,
                              void* d_out, int out_size, void* d_ws, size_t ws_size,
                              hipStream_t stream) {
  const float* Q    = (const float*)d_in[0];
  const float* K    = (const float*)d_in[1];
  const float* V    = (const float*)d_in[2];
  const float* mask = (const float*)d_in[3];
  const float* Wq   = (const float*)d_in[4];
  const float* bq   = (const float*)d_in[5];
  const float* Wk   = (const float*)d_in[6];
  const float* bk   = (const float*)d_in[7];
  const float* Wv   = (const float*)d_in[8];
  const float* bv   = (const float*)d_in[9];

  char* ws = (char*)d_ws;
  unsigned short* wt = (unsigned short*)ws;                  // 6MB: 3 x bf16 W^T
  unsigned short* qb = (unsigned short*)(ws + 6291456);      // 16MB [B,H,S,64]
  unsigned short* kb = (unsigned short*)(ws + 23068672);     // 16MB [B,H,S,64]
  unsigned short* vb = (unsigned short*)(ws + 39845888);     // 16MB [B,H,64,S]
  unsigned short* xb = (unsigned short*)(ws + 56623104);     // 48MB bf16 Q,K,V

  hipLaunchKernelGGL(wt_kernel, dim3(32, 32, 3), dim3(32, 32), 0, stream, Wq, Wk, Wv, wt);
  hipLaunchKernelGGL(cvt_kernel, dim3(4096, 3), dim3(256), 0, stream, Q, K, V, xb);
  hipLaunchKernelGGL(proj_kernel, dim3(64, 8, 3), dim3(256), 0, stream,
                     xb, wt, bq, bk, bv, qb, kb, vb);
  hipLaunchKernelGGL(attn_kernel, dim3(16, 16, 4), dim3(256), 0, stream,
                     qb, kb, vb, mask, (float*)d_out);
}